// Round 5
// baseline (150.418 us; speedup 1.0000x reference)
//
#include <hip/hip_runtime.h>

// Aspect-grouped 2-layer MLP — SINGLE dispatch (+1 tiny memset node).
// Grid (84 chunks, 4 h-slices, 2 d-halves) = 672 blocks, 512 thr each.
// Every block redundantly buckets the 1024 aspect_ids (ballot histogram +
// stable ballot scan -> its chunk's 16 sample ids), stages its d-half of the
// 16 X rows in LDS, computes a (16 samples x 64 cols x 384 d) partial with
// 4x4 register blocking, cross-wave LDS reduce, stores PRE-activation
// partials to ws. The last of a chunk's 8 blocks (threadfence+atomic) sums
// the 8 partials, applies b1+relu, layer 2 (+b2), writes out. Deterministic:
// fixed summation order, no fp atomics.

constexpr int D  = 768;
constexpr int H  = 256;
constexpr int NA = 20;
constexpr int NB = 1024;
constexpr int S  = 16;             // samples per chunk
constexpr int CH_CAP = 84;         // >= max chunks (<=82)
constexpr int HS = 4;              // 64-col slices
constexpr int DK = 2;              // d-halves
constexpr int DHALF = D / DK;      // 384
constexpr int ROWS  = DHALF / 8;   // 48 rows per wave
constexpr int XP    = DHALF + 4;   // padded LDS row

constexpr size_t WS_CNT_BYTES = 512;   // int cnt[CH_CAP] (+pad), memset to 0
constexpr size_t WS_NEEDED = WS_CNT_BYTES + (size_t)CH_CAP * DK * S * H * 4;

__device__ __forceinline__ float4 fma4(float x, float4 w, float4 a) {
    a.x = fmaf(x, w.x, a.x); a.y = fmaf(x, w.y, a.y);
    a.z = fmaf(x, w.z, a.z); a.w = fmaf(x, w.w, a.w);
    return a;
}

__global__ __launch_bounds__(512) void fused_mlp_kernel(
    const float* __restrict__ X,
    const int*   __restrict__ aids,
    const float* __restrict__ W1,
    const float* __restrict__ b1,
    const float* __restrict__ W2,
    const float* __restrict__ b2,
    float*       __restrict__ out,
    int*         __restrict__ cnt,     // [CH_CAP], zeroed each launch
    float*       __restrict__ part1)   // [CH_CAP][DK][S][H] pre-act partials
{
    __shared__ __align__(16) float smem[8192];   // 32 KB: ai/hist -> xs -> red
    __shared__ int sidx[S];
    __shared__ int isLast;

    const int t = threadIdx.x;
    const int w = t >> 6, l = t & 63;
    const int c  = blockIdx.x;
    const int hs = blockIdx.y;
    const int dk = blockIdx.z;

    int* ai   = reinterpret_cast<int*>(smem);   // [NB]
    int* hist = ai + NB;                        // [8][NA]
    int* cntf = hist + 8 * NA;                  // [NA]

    ai[t]       = aids[t];
    ai[t + 512] = aids[t + 512];
    __syncthreads();

    // per-wave histogram via 64-bit ballots (deterministic)
    {
        const int id0 = ai[w * 128 + l];
        const int id1 = ai[w * 128 + 64 + l];
        #pragma unroll
        for (int a = 0; a < NA; ++a) {
            const unsigned long long m0 = __ballot(id0 == a);
            const unsigned long long m1 = __ballot(id1 == a);
            if (l == 0) hist[w * NA + a] = __popcll(m0) + __popcll(m1);
        }
    }
    __syncthreads();
    if (t < NA) {
        int sum = 0;
        #pragma unroll
        for (int ww = 0; ww < 8; ++ww) sum += hist[ww * NA + t];
        cntf[t] = sum;
    }
    __syncthreads();

    // map chunk c -> (aspect aid, chunk index jj, valid count cv)
    int aid = -1, jj = 0, cv = 0;
    {
        int cb = 0;
        #pragma unroll
        for (int a = 0; a < NA; ++a) {
            const int n  = cntf[a];
            const int ca = (n + S - 1) / S;
            if (aid < 0 && c < cb + ca) {
                aid = a; jj = c - cb; cv = min(S, n - jj * S);
            }
            cb += ca;
        }
    }
    if (aid < 0) return;                        // c >= total chunks (uniform)

    // wave 0: stable extraction of occurrences jj*16 .. jj*16+cv-1
    if (w == 0) {
        const int j0 = jj * S;
        int running = 0;
        for (int base = 0; base < NB; base += 64) {
            const int id = ai[base + l];
            const unsigned long long m = __ballot(id == aid);
            const int pre = running + __popcll(m & ((1ull << l) - 1));
            if (id == aid) {
                const int r = pre - j0;
                if (r >= 0 && r < S) sidx[r] = base + l;
            }
            running += __popcll(m);
        }
    }
    __syncthreads();

    // stage this d-half of the 16 X rows (96 float4 each); overwrites ai/hist
    for (int i = t; i < S * (DHALF / 4); i += 512) {
        const int r = i / (DHALF / 4), c4 = i - r * (DHALF / 4);
        *reinterpret_cast<float4*>(&smem[r * XP + c4 * 4]) =
            *reinterpret_cast<const float4*>(
                X + (size_t)sidx[min(r, cv - 1)] * D + dk * DHALF + c4 * 4);
    }
    __syncthreads();

    const int sq = l >> 4;                      // sample quad 0..3
    const int cq = l & 15;                      // col quad within 64-col slice
    const float* xb = &smem[(sq * 4) * XP + w * ROWS];
    const float4* W1p = reinterpret_cast<const float4*>(W1 + (size_t)aid * (D * H))
                        + (size_t)(dk * DHALF + w * ROWS) * (H / 4) + hs * 16 + cq;

    float4 a0 = {0,0,0,0}, a1 = {0,0,0,0}, a2 = {0,0,0,0}, a3 = {0,0,0,0};
    #pragma unroll 4
    for (int d4 = 0; d4 < ROWS; d4 += 4) {
        const float4 x0 = *reinterpret_cast<const float4*>(xb + d4);
        const float4 x1 = *reinterpret_cast<const float4*>(xb + XP + d4);
        const float4 x2 = *reinterpret_cast<const float4*>(xb + 2 * XP + d4);
        const float4 x3 = *reinterpret_cast<const float4*>(xb + 3 * XP + d4);
        float4 wv;
        wv = W1p[(size_t)(d4 + 0) * (H / 4)];
        a0 = fma4(x0.x, wv, a0); a1 = fma4(x1.x, wv, a1);
        a2 = fma4(x2.x, wv, a2); a3 = fma4(x3.x, wv, a3);
        wv = W1p[(size_t)(d4 + 1) * (H / 4)];
        a0 = fma4(x0.y, wv, a0); a1 = fma4(x1.y, wv, a1);
        a2 = fma4(x2.y, wv, a2); a3 = fma4(x3.y, wv, a3);
        wv = W1p[(size_t)(d4 + 2) * (H / 4)];
        a0 = fma4(x0.z, wv, a0); a1 = fma4(x1.z, wv, a1);
        a2 = fma4(x2.z, wv, a2); a3 = fma4(x3.z, wv, a3);
        wv = W1p[(size_t)(d4 + 3) * (H / 4)];
        a0 = fma4(x0.w, wv, a0); a1 = fma4(x1.w, wv, a1);
        a2 = fma4(x2.w, wv, a2); a3 = fma4(x3.w, wv, a3);
    }
    __syncthreads();                            // done reading xs

    // cross-wave reduce: red[w][s][cq] float4 = 32 KB overlay
    float4* red = reinterpret_cast<float4*>(smem);
    red[(w * S + sq * 4 + 0) * 16 + cq] = a0;
    red[(w * S + sq * 4 + 1) * 16 + cq] = a1;
    red[(w * S + sq * 4 + 2) * 16 + cq] = a2;
    red[(w * S + sq * 4 + 3) * 16 + cq] = a3;
    __syncthreads();

    if (t < 256) {
        const int s = t >> 4, q = t & 15;
        float4 v = red[s * 16 + q];
        #pragma unroll
        for (int ww = 1; ww < 8; ++ww) {
            const float4 r = red[(ww * S + s) * 16 + q];
            v.x += r.x; v.y += r.y; v.z += r.z; v.w += r.w;
        }
        // store PRE-activation partial (no bias/relu — d is split across dk)
        *reinterpret_cast<float4*>(
            &part1[((size_t)(c * DK + dk) * S + s) * H + hs * 64 + q * 4]) = v;
    }

    // ---- last-block-done: release fence, per-chunk counter ----
    __threadfence();
    __syncthreads();
    if (t == 0) isLast = (atomicAdd(&cnt[c], 1) == DK * HS - 1);
    __syncthreads();
    if (!isLast) return;
    __threadfence();                            // acquire: see others' partials

    // winner: finish chunk c. 32 threads per sample, 8 cols each.
    {
        const int s = t >> 5;                   // 0..15
        const int m = t & 31;                   // 0..31
        const int col = m * 8;
        const float* pa = &part1[((size_t)(c * DK + 0) * S + s) * H + col];
        const float* pb = &part1[((size_t)(c * DK + 1) * S + s) * H + col];
        const float4 pa0 = reinterpret_cast<const float4*>(pa)[0];
        const float4 pa1 = reinterpret_cast<const float4*>(pa)[1];
        const float4 pb0 = reinterpret_cast<const float4*>(pb)[0];
        const float4 pb1 = reinterpret_cast<const float4*>(pb)[1];
        const float4 b10 = reinterpret_cast<const float4*>(b1 + (size_t)aid * H + col)[0];
        const float4 b11 = reinterpret_cast<const float4*>(b1 + (size_t)aid * H + col)[1];
        float4 h0, h1;
        h0.x = fmaxf(pa0.x + pb0.x + b10.x, 0.f);
        h0.y = fmaxf(pa0.y + pb0.y + b10.y, 0.f);
        h0.z = fmaxf(pa0.z + pb0.z + b10.z, 0.f);
        h0.w = fmaxf(pa0.w + pb0.w + b10.w, 0.f);
        h1.x = fmaxf(pa1.x + pb1.x + b11.x, 0.f);
        h1.y = fmaxf(pa1.y + pb1.y + b11.y, 0.f);
        h1.z = fmaxf(pa1.z + pb1.z + b11.z, 0.f);
        h1.w = fmaxf(pa1.w + pb1.w + b11.w, 0.f);

        const float4* W2v = reinterpret_cast<const float4*>(
            W2 + (size_t)aid * (H * 2) + col * 2);
        const float4 w0 = W2v[0], w1 = W2v[1], w2 = W2v[2], w3 = W2v[3];
        float p0 = h0.x * w0.x + h0.y * w0.z + h0.z * w1.x + h0.w * w1.z
                 + h1.x * w2.x + h1.y * w2.z + h1.z * w3.x + h1.w * w3.z;
        float p1 = h0.x * w0.y + h0.y * w0.w + h0.z * w1.y + h0.w * w1.w
                 + h1.x * w2.y + h1.y * w2.w + h1.z * w3.y + h1.w * w3.w;
        #pragma unroll
        for (int msk = 1; msk < 32; msk <<= 1) {
            p0 += __shfl_xor(p0, msk, 64);
            p1 += __shfl_xor(p1, msk, 64);
        }
        if (m == 0 && s < cv) {
            const float2 bias2 = reinterpret_cast<const float2*>(b2)[aid];
            reinterpret_cast<float2*>(out)[sidx[s]] =
                make_float2(p0 + bias2.x, p1 + bias2.y);
        }
    }
}

// ---------------- fallback (round-1 monolithic kernel) ----------------
__global__ __launch_bounds__(256, 4) void aspect_mlp_fallback(
    const float* __restrict__ X, const int* __restrict__ aspect_ids,
    const float* __restrict__ W1_embs, const float* __restrict__ b1_embs,
    const float* __restrict__ W2_embs, const float* __restrict__ b2_embs,
    float* __restrict__ out)
{
    __shared__ float xs[D];
    __shared__ float pl[4][H];
    __shared__ float red[4][2];
    const int b = blockIdx.x, t = threadIdx.x, w = t >> 6, l = t & 63;
    const int aid = aspect_ids[b];
    const float4* Xr = reinterpret_cast<const float4*>(X + (size_t)b * D);
    if (t < D / 4) reinterpret_cast<float4*>(xs)[t] = Xr[t];
    __syncthreads();
    const float4* W1v = reinterpret_cast<const float4*>(W1_embs + (size_t)aid * (D * H));
    float4 acc = make_float4(0.f, 0.f, 0.f, 0.f);
    const int d0 = w * (D / 4);
    for (int d = d0; d < d0 + D / 4; ++d) {
        const float xv = xs[d];
        const float4 wv = W1v[d * (H / 4) + l];
        acc.x = fmaf(xv, wv.x, acc.x); acc.y = fmaf(xv, wv.y, acc.y);
        acc.z = fmaf(xv, wv.z, acc.z); acc.w = fmaf(xv, wv.w, acc.w);
    }
    reinterpret_cast<float4*>(pl[w])[l] = acc;
    __syncthreads();
    const float o = fmaxf(pl[0][t] + pl[1][t] + pl[2][t] + pl[3][t] + b1_embs[aid * H + t], 0.f);
    const float2 w2 = reinterpret_cast<const float2*>(W2_embs)[aid * H + t];
    float p0 = o * w2.x, p1 = o * w2.y;
    for (int s = 32; s; s >>= 1) { p0 += __shfl_xor(p0, s, 64); p1 += __shfl_xor(p1, s, 64); }
    if (l == 0) { red[w][0] = p0; red[w][1] = p1; }
    __syncthreads();
    if (t == 0) {
        const float2 bias2 = reinterpret_cast<const float2*>(b2_embs)[aid];
        out[b * 2 + 0] = red[0][0] + red[1][0] + red[2][0] + red[3][0] + bias2.x;
        out[b * 2 + 1] = red[0][1] + red[1][1] + red[2][1] + red[3][1] + bias2.y;
    }
}

extern "C" void kernel_launch(void* const* d_in, const int* in_sizes, int n_in,
                              void* d_out, int out_size, void* d_ws, size_t ws_size,
                              hipStream_t stream) {
    const float* X          = (const float*)d_in[0];
    const int*   aspect_ids = (const int*)d_in[1];
    const float* W1_embs    = (const float*)d_in[2];
    const float* b1_embs    = (const float*)d_in[3];
    const float* W2_embs    = (const float*)d_in[4];
    const float* b2_embs    = (const float*)d_in[5];
    float*       out        = (float*)d_out;

    const int Brt = in_sizes[0] / D;
    const int na  = in_sizes[2] / (D * H);

    if (Brt != NB || na != NA || ws_size < WS_NEEDED) {
        aspect_mlp_fallback<<<Brt, 256, 0, stream>>>(
            X, aspect_ids, W1_embs, b1_embs, W2_embs, b2_embs, out);
        return;
    }

    int*   cnt   = (int*)d_ws;
    float* part1 = (float*)((char*)d_ws + WS_CNT_BYTES);

    hipMemsetAsync(d_ws, 0, WS_CNT_BYTES, stream);   // graph-capturable
    fused_mlp_kernel<<<dim3(CH_CAP, HS, DK), 512, 0, stream>>>(
        X, aspect_ids, W1_embs, b1_embs, W2_embs, b2_embs, out, cnt, part1);
}

// Round 6
// 34.571 us; speedup vs baseline: 4.3510x; 4.3510x over previous
//
#include <hip/hip_runtime.h>

// Aspect-grouped 2-layer MLP — one memset node + ONE kernel, no fences.
// Grid (84 chunks, 4 h-slices) x 512 thr. Every block redundantly buckets the
// 1024 aspect_ids (ballot histogram + stable ballot scan -> its chunk's 16
// sample ids), stages the 16 X rows (full D=768) in LDS, computes a
// (16 samples x 64 cols) slab with 4x4 register blocking over its wave's
// 96-row d-slice, LDS cross-wave reduce, then bias+relu+layer2 for its 64
// cols and atomicAdds the float2 partial logits into out (hs==0 adds b2).
// out is zeroed by a captured hipMemsetAsync each launch.

constexpr int D  = 768;
constexpr int H  = 256;
constexpr int NA = 20;
constexpr int NB = 1024;
constexpr int S  = 16;            // samples per chunk
constexpr int CH_CAP = 84;        // >= max chunks (<= 64+20-ish)
constexpr int DP = D + 4;         // padded LDS row

__device__ __forceinline__ float4 fma4(float x, float4 w, float4 a) {
    a.x = fmaf(x, w.x, a.x); a.y = fmaf(x, w.y, a.y);
    a.z = fmaf(x, w.z, a.z); a.w = fmaf(x, w.w, a.w);
    return a;
}

__global__ __launch_bounds__(512, 2) void fused_mlp_kernel(
    const float* __restrict__ X,
    const int*   __restrict__ aids,
    const float* __restrict__ W1,
    const float* __restrict__ b1,
    const float* __restrict__ W2,
    const float* __restrict__ b2,
    float*       __restrict__ out)     // [NB][2], zeroed each launch
{
    __shared__ __align__(16) float smem[S * DP];   // ai/hist -> xs -> red
    __shared__ int sidx[S];

    const int t = threadIdx.x;
    const int w = t >> 6, l = t & 63;
    const int c = blockIdx.x, hs = blockIdx.y;

    int* ai   = reinterpret_cast<int*>(smem);   // [NB]
    int* hist = ai + NB;                        // [8][NA]
    int* cntf = hist + 8 * NA;                  // [NA]

    ai[t]       = aids[t];
    ai[t + 512] = aids[t + 512];
    __syncthreads();

    // per-wave histogram via 64-bit ballots (deterministic)
    {
        const int id0 = ai[w * 128 + l];
        const int id1 = ai[w * 128 + 64 + l];
        #pragma unroll
        for (int a = 0; a < NA; ++a) {
            const unsigned long long m0 = __ballot(id0 == a);
            const unsigned long long m1 = __ballot(id1 == a);
            if (l == 0) hist[w * NA + a] = __popcll(m0) + __popcll(m1);
        }
    }
    __syncthreads();
    if (t < NA) {
        int sum = 0;
        #pragma unroll
        for (int ww = 0; ww < 8; ++ww) sum += hist[ww * NA + t];
        cntf[t] = sum;
    }
    __syncthreads();

    // map chunk c -> (aspect aid, chunk index jj, valid count cv)
    int aid = -1, jj = 0, cv = 0;
    {
        int cb = 0;
        #pragma unroll
        for (int a = 0; a < NA; ++a) {
            const int n  = cntf[a];
            const int ca = (n + S - 1) / S;
            if (aid < 0 && c < cb + ca) {
                aid = a; jj = c - cb; cv = min(S, n - jj * S);
            }
            cb += ca;
        }
    }
    if (aid < 0) return;                        // c >= total chunks (uniform)

    // wave 0: stable extraction of occurrences jj*16 .. jj*16+cv-1
    if (w == 0) {
        const int j0 = jj * S;
        int running = 0;
        for (int base = 0; base < NB; base += 64) {
            const int id = ai[base + l];
            const unsigned long long m = __ballot(id == aid);
            const int pre = running + __popcll(m & ((1ull << l) - 1));
            if (id == aid) {
                const int r = pre - j0;
                if (r >= 0 && r < S) sidx[r] = base + l;
            }
            running += __popcll(m);
        }
    }
    __syncthreads();

    // stage 16 full X rows (192 float4 each); overwrites ai/hist/cntf
    for (int i = t; i < S * (D / 4); i += 512) {
        const int r = i / (D / 4), c4 = i - r * (D / 4);
        *reinterpret_cast<float4*>(&smem[r * DP + c4 * 4]) =
            reinterpret_cast<const float4*>(X + (size_t)sidx[min(r, cv - 1)] * D)[c4];
    }
    __syncthreads();

    const int sq = l >> 4;                      // sample quad 0..3
    const int cq = l & 15;                      // col quad within 64-col slice
    const int d0 = w * (D / 8);                 // 96 rows per wave
    const float* xb = &smem[(sq * 4) * DP + d0];
    const float4* W1p = reinterpret_cast<const float4*>(W1 + (size_t)aid * (D * H))
                        + (size_t)d0 * (H / 4) + hs * 16 + cq;

    float4 a0 = {0,0,0,0}, a1 = {0,0,0,0}, a2 = {0,0,0,0}, a3 = {0,0,0,0};
    #pragma unroll 3
    for (int d4 = 0; d4 < D / 8; d4 += 4) {
        const float4 x0 = *reinterpret_cast<const float4*>(xb + d4);
        const float4 x1 = *reinterpret_cast<const float4*>(xb + DP + d4);
        const float4 x2 = *reinterpret_cast<const float4*>(xb + 2 * DP + d4);
        const float4 x3 = *reinterpret_cast<const float4*>(xb + 3 * DP + d4);
        float4 wv;
        wv = W1p[(size_t)(d4 + 0) * (H / 4)];
        a0 = fma4(x0.x, wv, a0); a1 = fma4(x1.x, wv, a1);
        a2 = fma4(x2.x, wv, a2); a3 = fma4(x3.x, wv, a3);
        wv = W1p[(size_t)(d4 + 1) * (H / 4)];
        a0 = fma4(x0.y, wv, a0); a1 = fma4(x1.y, wv, a1);
        a2 = fma4(x2.y, wv, a2); a3 = fma4(x3.y, wv, a3);
        wv = W1p[(size_t)(d4 + 2) * (H / 4)];
        a0 = fma4(x0.z, wv, a0); a1 = fma4(x1.z, wv, a1);
        a2 = fma4(x2.z, wv, a2); a3 = fma4(x3.z, wv, a3);
        wv = W1p[(size_t)(d4 + 3) * (H / 4)];
        a0 = fma4(x0.w, wv, a0); a1 = fma4(x1.w, wv, a1);
        a2 = fma4(x2.w, wv, a2); a3 = fma4(x3.w, wv, a3);
    }
    __syncthreads();                            // done reading xs

    // cross-wave reduce: red[w][s][cq] float4 = 32 KB overlay
    float4* red = reinterpret_cast<float4*>(smem);
    red[(w * S + sq * 4 + 0) * 16 + cq] = a0;
    red[(w * S + sq * 4 + 1) * 16 + cq] = a1;
    red[(w * S + sq * 4 + 2) * 16 + cq] = a2;
    red[(w * S + sq * 4 + 3) * 16 + cq] = a3;
    __syncthreads();

    if (t < 256) {
        const int s = t >> 4, q = t & 15;
        float4 v = red[s * 16 + q];
        #pragma unroll
        for (int ww = 1; ww < 8; ++ww) {
            const float4 r = red[(ww * S + s) * 16 + q];
            v.x += r.x; v.y += r.y; v.z += r.z; v.w += r.w;
        }
        const float4 bv = reinterpret_cast<const float4*>(
            b1 + (size_t)aid * H + hs * 64)[q];
        float4 o;
        o.x = fmaxf(v.x + bv.x, 0.f);
        o.y = fmaxf(v.y + bv.y, 0.f);
        o.z = fmaxf(v.z + bv.z, 0.f);
        o.w = fmaxf(v.w + bv.w, 0.f);

        const float4* W2v = reinterpret_cast<const float4*>(
            W2 + (size_t)aid * (H * 2) + hs * 128 + q * 8);
        const float4 w2a = W2v[0];
        const float4 w2b = W2v[1];
        float p0 = o.x * w2a.x + o.y * w2a.z + o.z * w2b.x + o.w * w2b.z;
        float p1 = o.x * w2a.y + o.y * w2a.w + o.z * w2b.y + o.w * w2b.w;
        #pragma unroll
        for (int m = 1; m < 16; m <<= 1) {
            p0 += __shfl_xor(p0, m, 64);
            p1 += __shfl_xor(p1, m, 64);
        }
        if (q == 0 && s < cv) {                 // guard: atomics not idempotent
            if (hs == 0) {                       // fold b2 in exactly once
                const float2 bias2 = reinterpret_cast<const float2*>(b2)[aid];
                p0 += bias2.x; p1 += bias2.y;
            }
            atomicAdd(&out[sidx[s] * 2 + 0], p0);
            atomicAdd(&out[sidx[s] * 2 + 1], p1);
        }
    }
}

// ---------------- fallback (round-1 monolithic kernel) ----------------
__global__ __launch_bounds__(256, 4) void aspect_mlp_fallback(
    const float* __restrict__ X, const int* __restrict__ aspect_ids,
    const float* __restrict__ W1_embs, const float* __restrict__ b1_embs,
    const float* __restrict__ W2_embs, const float* __restrict__ b2_embs,
    float* __restrict__ out)
{
    __shared__ float xs[D];
    __shared__ float pl[4][H];
    __shared__ float red[4][2];
    const int b = blockIdx.x, t = threadIdx.x, w = t >> 6, l = t & 63;
    const int aid = aspect_ids[b];
    const float4* Xr = reinterpret_cast<const float4*>(X + (size_t)b * D);
    if (t < D / 4) reinterpret_cast<float4*>(xs)[t] = Xr[t];
    __syncthreads();
    const float4* W1v = reinterpret_cast<const float4*>(W1_embs + (size_t)aid * (D * H));
    float4 acc = make_float4(0.f, 0.f, 0.f, 0.f);
    const int d0 = w * (D / 4);
    for (int d = d0; d < d0 + D / 4; ++d) {
        const float xv = xs[d];
        const float4 wv = W1v[d * (H / 4) + l];
        acc.x = fmaf(xv, wv.x, acc.x); acc.y = fmaf(xv, wv.y, acc.y);
        acc.z = fmaf(xv, wv.z, acc.z); acc.w = fmaf(xv, wv.w, acc.w);
    }
    reinterpret_cast<float4*>(pl[w])[l] = acc;
    __syncthreads();
    const float o = fmaxf(pl[0][t] + pl[1][t] + pl[2][t] + pl[3][t] + b1_embs[aid * H + t], 0.f);
    const float2 w2 = reinterpret_cast<const float2*>(W2_embs)[aid * H + t];
    float p0 = o * w2.x, p1 = o * w2.y;
    for (int s = 32; s; s >>= 1) { p0 += __shfl_xor(p0, s, 64); p1 += __shfl_xor(p1, s, 64); }
    if (l == 0) { red[w][0] = p0; red[w][1] = p1; }
    __syncthreads();
    if (t == 0) {
        const float2 bias2 = reinterpret_cast<const float2*>(b2_embs)[aid];
        out[b * 2 + 0] = red[0][0] + red[1][0] + red[2][0] + red[3][0] + bias2.x;
        out[b * 2 + 1] = red[0][1] + red[1][1] + red[2][1] + red[3][1] + bias2.y;
    }
}

extern "C" void kernel_launch(void* const* d_in, const int* in_sizes, int n_in,
                              void* d_out, int out_size, void* d_ws, size_t ws_size,
                              hipStream_t stream) {
    const float* X          = (const float*)d_in[0];
    const int*   aspect_ids = (const int*)d_in[1];
    const float* W1_embs    = (const float*)d_in[2];
    const float* b1_embs    = (const float*)d_in[3];
    const float* W2_embs    = (const float*)d_in[4];
    const float* b2_embs    = (const float*)d_in[5];
    float*       out        = (float*)d_out;

    const int Brt = in_sizes[0] / D;
    const int na  = in_sizes[2] / (D * H);

    if (Brt != NB || na != NA) {
        aspect_mlp_fallback<<<Brt, 256, 0, stream>>>(
            X, aspect_ids, W1_embs, b1_embs, W2_embs, b2_embs, out);
        return;
    }

    hipMemsetAsync(d_out, 0, (size_t)out_size * sizeof(float), stream);
    fused_mlp_kernel<<<dim3(CH_CAP, 4), 512, 0, stream>>>(
        X, aspect_ids, W1_embs, b1_embs, W2_embs, b2_embs, out);
}

// Round 7
// 24.580 us; speedup vs baseline: 6.1196x; 1.4065x over previous
//
#include <hip/hip_runtime.h>

// Aspect-owned tiled 2-layer MLP, 2 dispatches, no atomics/fences.
//   gemm1:  grid (20 aspects, 4 col-slices, 8 d-slices) x 256 thr.
//           Block stages its W1 tile (96 rows x 64 cols fp32 = 25KB) in LDS
//           ONCE, ballot-scans the 1024 aspect_ids for its aspect's sample
//           list, then per 16-sample chunk: stage X (16x96) in LDS, compute
//           from LDS x LDS with 4-sample x 4-col register blocking (waves
//           split K=96 into 4x24), LDS cross-wave reduce, write disjoint
//           pre-activation partials part[sample][dk][col].
//   finish: per sample: sum 8 dk-partials + b1, ReLU, x W2 + b2 -> out.

constexpr int D  = 768;
constexpr int H  = 256;
constexpr int NA = 20;
constexpr int NB = 1024;
constexpr int S  = 16;            // samples per chunk
constexpr int DKN = 8;            // d-slices
constexpr int KS  = D / DKN;      // 96 rows per block
constexpr int HSN = 4;            // 64-col slices
constexpr int KT  = KS / 4;       // 24 k per wave
constexpr int QR  = KS / 4;       // 24 float4 per staged x row
constexpr int XROW  = KS + 4;     // 100 (pad)
constexpr int W1ROW = 68;         // 64 + 4 (pad)

// smem layout (float offsets)
constexpr int SM_XT   = KS * W1ROW;          // w1t: [96][68]      = 6528
constexpr int SM_RED  = SM_XT + S * XROW;    // xt:  [16][100]     @6528
constexpr int SM_SIDX = SM_RED + 4096;       // red: [4][16][16]f4 @8128 (16KB)
constexpr int SM_TOT  = SM_SIDX + NB;        // sidx:[1024] int    @12224
                                             // total 13248 fl = 52992 B -> 3/CU
constexpr size_t WS_NEEDED = (size_t)NB * DKN * H * 4;   // part: 8 MB

__device__ __forceinline__ float4 fma4(float x, float4 w, float4 a) {
    a.x = fmaf(x, w.x, a.x); a.y = fmaf(x, w.y, a.y);
    a.z = fmaf(x, w.z, a.z); a.w = fmaf(x, w.w, a.w);
    return a;
}

__global__ __launch_bounds__(256, 3) void gemm1_kernel(
    const float* __restrict__ X,
    const int*   __restrict__ aids,
    const float* __restrict__ W1,
    float*       __restrict__ part)    // [NB][DKN][H]
{
    __shared__ __align__(16) float smem[SM_TOT];
    __shared__ int n_sh;

    float*  w1t  = smem;
    float*  xt   = smem + SM_XT;
    float4* red4 = reinterpret_cast<float4*>(smem + SM_RED);
    int*    sidx = reinterpret_cast<int*>(smem + SM_SIDX);
    int*    ai   = reinterpret_cast<int*>(smem + SM_RED);   // prologue overlay

    const int t = threadIdx.x;
    const int w = t >> 6, l = t & 63;
    const int aid = blockIdx.x;        // aspect
    const int hs  = blockIdx.y;        // 64-col slice
    const int dk  = blockIdx.z;        // 96-row d-slice

    // stage aspect ids (overlaid on red region)
    ai[t]       = aids[t];
    ai[t + 256] = aids[t + 256];
    ai[t + 512] = aids[t + 512];
    ai[t + 768] = aids[t + 768];

    // stage W1 tile ONCE: rows dk*96.., cols hs*64.. (bulk coalesced)
    const float* W1s = W1 + (size_t)aid * D * H + (size_t)dk * KS * H + hs * 64;
    for (int i = t; i < KS * 16; i += 256) {
        const int r = i >> 4, c = i & 15;
        *reinterpret_cast<float4*>(&w1t[r * W1ROW + c * 4]) =
            *reinterpret_cast<const float4*>(&W1s[(size_t)r * H + c * 4]);
    }
    __syncthreads();

    // wave 0: stable ballot-scan -> this aspect's full sample list
    if (w == 0) {
        int run = 0;
        for (int base = 0; base < NB; base += 64) {
            const int id = ai[base + l];
            const unsigned long long m = __ballot(id == aid);
            const int pre = run + __popcll(m & ((1ull << l) - 1));
            if (id == aid) sidx[pre] = base + l;
            run += __popcll(m);
        }
        if (l == 0) n_sh = run;
    }
    __syncthreads();
    const int n = n_sh;

    const int sq = l >> 4;            // sample quad 0..3
    const int cq = l & 15;            // col quad 0..15
    const float* wb = w1t + (w * KT) * W1ROW + cq * 4;

    for (int ch = 0; ch * S < n; ++ch) {
        const int cv = min(S, n - ch * S);

        // stage 16 X rows (this d-slice: 24 float4 each)
        for (int i = t; i < S * QR; i += 256) {
            const int r = i / QR, q = i - r * QR;
            *reinterpret_cast<float4*>(&xt[r * XROW + q * 4]) =
                *reinterpret_cast<const float4*>(
                    &X[(size_t)sidx[ch * S + min(r, cv - 1)] * D + dk * KS + q * 4]);
        }
        __syncthreads();

        // LDS x LDS compute: wave w covers k in [w*24, w*24+24)
        const float* xb = xt + (sq * 4) * XROW + w * KT;
        float4 a0 = {0,0,0,0}, a1 = {0,0,0,0}, a2 = {0,0,0,0}, a3 = {0,0,0,0};
        #pragma unroll
        for (int k4 = 0; k4 < KT; k4 += 4) {
            const float4 x0 = *reinterpret_cast<const float4*>(xb + k4);
            const float4 x1 = *reinterpret_cast<const float4*>(xb + XROW + k4);
            const float4 x2 = *reinterpret_cast<const float4*>(xb + 2 * XROW + k4);
            const float4 x3 = *reinterpret_cast<const float4*>(xb + 3 * XROW + k4);
            const float* wp = wb + k4 * W1ROW;
            float4 wv;
            wv = *reinterpret_cast<const float4*>(wp);
            a0 = fma4(x0.x, wv, a0); a1 = fma4(x1.x, wv, a1);
            a2 = fma4(x2.x, wv, a2); a3 = fma4(x3.x, wv, a3);
            wv = *reinterpret_cast<const float4*>(wp + W1ROW);
            a0 = fma4(x0.y, wv, a0); a1 = fma4(x1.y, wv, a1);
            a2 = fma4(x2.y, wv, a2); a3 = fma4(x3.y, wv, a3);
            wv = *reinterpret_cast<const float4*>(wp + 2 * W1ROW);
            a0 = fma4(x0.z, wv, a0); a1 = fma4(x1.z, wv, a1);
            a2 = fma4(x2.z, wv, a2); a3 = fma4(x3.z, wv, a3);
            wv = *reinterpret_cast<const float4*>(wp + 3 * W1ROW);
            a0 = fma4(x0.w, wv, a0); a1 = fma4(x1.w, wv, a1);
            a2 = fma4(x2.w, wv, a2); a3 = fma4(x3.w, wv, a3);
        }

        // cross-wave reduce
        red4[(w * 16 + sq * 4 + 0) * 16 + cq] = a0;
        red4[(w * 16 + sq * 4 + 1) * 16 + cq] = a1;
        red4[(w * 16 + sq * 4 + 2) * 16 + cq] = a2;
        red4[(w * 16 + sq * 4 + 3) * 16 + cq] = a3;
        __syncthreads();

        {
            const int s = t >> 4, q = t & 15;
            float4 v = red4[s * 16 + q];
            #pragma unroll
            for (int ww = 1; ww < 4; ++ww) {
                const float4 r = red4[ww * 256 + s * 16 + q];
                v.x += r.x; v.y += r.y; v.z += r.z; v.w += r.w;
            }
            if (s < cv) {
                const int sid = sidx[ch * S + s];
                *reinterpret_cast<float4*>(
                    &part[((size_t)sid * DKN + dk) * H + hs * 64 + q * 4]) = v;
            }
        }
        // no trailing sync needed: next X-stage touches xt only; the sync
        // after it orders red reuse.
    }
}

__global__ __launch_bounds__(256) void finish_kernel(
    const int*   __restrict__ aids,
    const float* __restrict__ part,
    const float* __restrict__ b1,
    const float* __restrict__ W2,
    const float* __restrict__ b2,
    float*       __restrict__ out)
{
    const int w = threadIdx.x >> 6, l = threadIdx.x & 63;
    const int s = blockIdx.x * 4 + w;       // one sample per wave
    const int aid = aids[s];

    const float* ps = part + (size_t)s * DKN * H + l * 4;
    float4 v = {0,0,0,0};
    #pragma unroll
    for (int dk = 0; dk < DKN; ++dk) {
        const float4 r = *reinterpret_cast<const float4*>(ps + dk * H);
        v.x += r.x; v.y += r.y; v.z += r.z; v.w += r.w;
    }
    const float4 bv = *reinterpret_cast<const float4*>(&b1[(size_t)aid * H + l * 4]);
    float4 o;
    o.x = fmaxf(v.x + bv.x, 0.f);
    o.y = fmaxf(v.y + bv.y, 0.f);
    o.z = fmaxf(v.z + bv.z, 0.f);
    o.w = fmaxf(v.w + bv.w, 0.f);

    const float4* W2v = reinterpret_cast<const float4*>(&W2[(size_t)aid * H * 2 + l * 8]);
    const float4 w2a = W2v[0], w2b = W2v[1];
    float p0 = o.x * w2a.x + o.y * w2a.z + o.z * w2b.x + o.w * w2b.z;
    float p1 = o.x * w2a.y + o.y * w2a.w + o.z * w2b.y + o.w * w2b.w;
    #pragma unroll
    for (int m = 1; m < 64; m <<= 1) {
        p0 += __shfl_xor(p0, m, 64);
        p1 += __shfl_xor(p1, m, 64);
    }
    if (l == 0) {
        const float2 bias2 = reinterpret_cast<const float2*>(b2)[aid];
        reinterpret_cast<float2*>(out)[s] = make_float2(p0 + bias2.x, p1 + bias2.y);
    }
}

// ---------------- fallback (round-1 monolithic kernel) ----------------
__global__ __launch_bounds__(256, 4) void aspect_mlp_fallback(
    const float* __restrict__ X, const int* __restrict__ aspect_ids,
    const float* __restrict__ W1_embs, const float* __restrict__ b1_embs,
    const float* __restrict__ W2_embs, const float* __restrict__ b2_embs,
    float* __restrict__ out)
{
    __shared__ float xs[D];
    __shared__ float pl[4][H];
    __shared__ float red[4][2];
    const int b = blockIdx.x, t = threadIdx.x, w = t >> 6, l = t & 63;
    const int aid = aspect_ids[b];
    const float4* Xr = reinterpret_cast<const float4*>(X + (size_t)b * D);
    if (t < D / 4) reinterpret_cast<float4*>(xs)[t] = Xr[t];
    __syncthreads();
    const float4* W1v = reinterpret_cast<const float4*>(W1_embs + (size_t)aid * (D * H));
    float4 acc = make_float4(0.f, 0.f, 0.f, 0.f);
    const int d0 = w * (D / 4);
    for (int d = d0; d < d0 + D / 4; ++d) {
        const float xv = xs[d];
        const float4 wv = W1v[d * (H / 4) + l];
        acc.x = fmaf(xv, wv.x, acc.x); acc.y = fmaf(xv, wv.y, acc.y);
        acc.z = fmaf(xv, wv.z, acc.z); acc.w = fmaf(xv, wv.w, acc.w);
    }
    reinterpret_cast<float4*>(pl[w])[l] = acc;
    __syncthreads();
    const float o = fmaxf(pl[0][t] + pl[1][t] + pl[2][t] + pl[3][t] + b1_embs[aid * H + t], 0.f);
    const float2 w2 = reinterpret_cast<const float2*>(W2_embs)[aid * H + t];
    float p0 = o * w2.x, p1 = o * w2.y;
    for (int s = 32; s; s >>= 1) { p0 += __shfl_xor(p0, s, 64); p1 += __shfl_xor(p1, s, 64); }
    if (l == 0) { red[w][0] = p0; red[w][1] = p1; }
    __syncthreads();
    if (t == 0) {
        const float2 bias2 = reinterpret_cast<const float2*>(b2_embs)[aid];
        out[b * 2 + 0] = red[0][0] + red[1][0] + red[2][0] + red[3][0] + bias2.x;
        out[b * 2 + 1] = red[0][1] + red[1][1] + red[2][1] + red[3][1] + bias2.y;
    }
}

extern "C" void kernel_launch(void* const* d_in, const int* in_sizes, int n_in,
                              void* d_out, int out_size, void* d_ws, size_t ws_size,
                              hipStream_t stream) {
    const float* X          = (const float*)d_in[0];
    const int*   aspect_ids = (const int*)d_in[1];
    const float* W1_embs    = (const float*)d_in[2];
    const float* b1_embs    = (const float*)d_in[3];
    const float* W2_embs    = (const float*)d_in[4];
    const float* b2_embs    = (const float*)d_in[5];
    float*       out        = (float*)d_out;

    const int Brt = in_sizes[0] / D;
    const int na  = in_sizes[2] / (D * H);

    if (Brt != NB || na != NA || ws_size < WS_NEEDED) {
        aspect_mlp_fallback<<<Brt, 256, 0, stream>>>(
            X, aspect_ids, W1_embs, b1_embs, W2_embs, b2_embs, out);
        return;
    }

    float* part = (float*)d_ws;

    gemm1_kernel<<<dim3(NA, HSN, DKN), 256, 0, stream>>>(
        X, aspect_ids, W1_embs, part);
    finish_kernel<<<NB / 4, 256, 0, stream>>>(
        aspect_ids, part, b1_embs, W2_embs, b2_embs, out);
}